// Round 4
// baseline (363.192 us; speedup 1.0000x reference)
//
#include <hip/hip_runtime.h>
#include <hip/hip_bf16.h>

#define BB 512
#define TT 300
#define IN_S 128
#define IN_D 64
#define HS 256
#define HD 128
#define CD 512  // 2*HD + HS

typedef __attribute__((ext_vector_type(8))) short bf16x8;
typedef __attribute__((ext_vector_type(4))) float f32x4;
typedef unsigned short ushort_t;

static __device__ __forceinline__ ushort_t f2bf(float x) {
    unsigned u = __builtin_bit_cast(unsigned, x);
    unsigned r = (u + 0x7FFFu + ((u >> 16) & 1u)) >> 16;  // RNE
    return (ushort_t)r;
}

// ---------------------------------------------------------------------------
// prep: f32 weights -> bf16 workspace copies; fused RNN bias sums.
// ---------------------------------------------------------------------------
__global__ __launch_bounds__(256) void prep_kernel(
    const float* __restrict__ wd, const float* __restrict__ wihf, const float* __restrict__ wihb,
    const float* __restrict__ whhf, const float* __restrict__ whhb,
    const float* __restrict__ bif, const float* __restrict__ bhf,
    const float* __restrict__ bib, const float* __restrict__ bhb,
    ushort_t* __restrict__ wd_bf, ushort_t* __restrict__ wihf_bf, ushort_t* __restrict__ wihb_bf,
    ushort_t* __restrict__ whhf_bf, ushort_t* __restrict__ whhb_bf,
    float* __restrict__ bsf, float* __restrict__ bsb)
{
    const int i = blockIdx.x * 256 + threadIdx.x;  // < 16384
    if (i < HD * IN_D) wd_bf[i] = f2bf(wd[i]);
    wihf_bf[i] = f2bf(wihf[i]);
    wihb_bf[i] = f2bf(wihb[i]);
    whhf_bf[i] = f2bf(whhf[i]);
    whhb_bf[i] = f2bf(whhb[i]);
    if (i < HD) { bsf[i] = bif[i] + bhf[i]; bsb[i] = bib[i] + bhb[i]; }
}

// ---------------------------------------------------------------------------
// Kernel A (validated r0): static MLP + static head dot.
// ---------------------------------------------------------------------------
__global__ __launch_bounds__(256) void static_head_kernel(
    const float* __restrict__ xs, const int* __restrict__ norder,
    const float* __restrict__ w1, const float* __restrict__ b1,
    const float* __restrict__ w2, const float* __restrict__ b2,
    const float* __restrict__ fcw, const float* __restrict__ fcb,
    float* __restrict__ ds)
{
    __shared__ float xb[IN_S];
    __shared__ float s1[HS];
    __shared__ float red[4];
    const int b = blockIdx.x, tid = threadIdx.x;
    if (tid < IN_S) xb[tid] = xs[(size_t)b * IN_S + tid];
    __syncthreads();

    float a0 = 0.f, a1 = 0.f, a2 = 0.f, a3 = 0.f;
    {
        const float4* wsrc = (const float4*)(w1 + (size_t)tid * IN_S);
        const float4* x4 = (const float4*)xb;
#pragma unroll
        for (int i = 0; i < IN_S / 4; ++i) {
            float4 w = wsrc[i], x = x4[i];
            a0 = fmaf(w.x, x.x, a0); a1 = fmaf(w.y, x.y, a1);
            a2 = fmaf(w.z, x.z, a2); a3 = fmaf(w.w, x.w, a3);
        }
    }
    s1[tid] = fmaxf(b1[tid] + ((a0 + a1) + (a2 + a3)), 0.f);
    __syncthreads();

    a0 = a1 = a2 = a3 = 0.f;
    {
        const float4* wsrc = (const float4*)(w2 + (size_t)tid * HS);
        const float4* x4 = (const float4*)s1;
#pragma unroll
        for (int i = 0; i < HS / 4; ++i) {
            float4 w = wsrc[i], x = x4[i];
            a0 = fmaf(w.x, x.x, a0); a1 = fmaf(w.y, x.y, a1);
            a2 = fmaf(w.z, x.z, a2); a3 = fmaf(w.w, x.w, a3);
        }
    }
    float s2 = fmaxf(b2[tid] + ((a0 + a1) + (a2 + a3)), 0.f);

    const int n = norder[b];
    float p = s2 * fcw[(size_t)n * CD + tid];
#pragma unroll
    for (int o = 32; o >= 1; o >>= 1) p += __shfl_down(p, o);
    if ((tid & 63) == 0) red[tid >> 6] = p;
    __syncthreads();
    if (tid == 0) ds[b] = red[0] + red[1] + red[2] + red[3] + fcb[n];
}

// ---------------------------------------------------------------------------
// proj (validated r2, unchanged): MFMA bf16 projection + RNN input precompute.
// ---------------------------------------------------------------------------
__global__ __launch_bounds__(256) void proj_kernel(
    const float* __restrict__ xd, const ushort_t* __restrict__ wd_bf,
    const float* __restrict__ bd,
    const ushort_t* __restrict__ wihf_bf, const ushort_t* __restrict__ wihb_bf,
    const float* __restrict__ bsf, const float* __restrict__ bsb,
    ushort_t* __restrict__ preF, ushort_t* __restrict__ preB)
{
    __shared__ char lds[49152];
    char* dbase = lds;
    char* xbase = lds + 32768;
    const int tid = threadIdx.x;
    const int m0 = blockIdx.x * 128;

    {
        const int row = tid >> 1, half = tid & 1;
        const int swz = (row & 7) << 4;
        const float4* src = (const float4*)(xd + (size_t)(m0 + row) * IN_D + half * 32);
#pragma unroll
        for (int i = 0; i < 4; ++i) {
            float4 a = src[2 * i], b = src[2 * i + 1];
            bf16x8 v;
            v[0] = (short)f2bf(a.x); v[1] = (short)f2bf(a.y);
            v[2] = (short)f2bf(a.z); v[3] = (short)f2bf(a.w);
            v[4] = (short)f2bf(b.x); v[5] = (short)f2bf(b.y);
            v[6] = (short)f2bf(b.z); v[7] = (short)f2bf(b.w);
            *(bf16x8*)(xbase + ((row * 128 + half * 64 + i * 16) ^ swz)) = v;
        }
    }
    __syncthreads();

    const int w = tid >> 6, l = tid & 63;
    const int lr = l & 15, lg = l >> 4;

    f32x4 acc[2][8];
#pragma unroll
    for (int mt = 0; mt < 2; ++mt)
#pragma unroll
        for (int nt = 0; nt < 8; ++nt) acc[mt][nt] = (f32x4){0.f, 0.f, 0.f, 0.f};

    for (int kk = 0; kk < 2; ++kk) {
        bf16x8 a[2], b[8];
#pragma unroll
        for (int mt = 0; mt < 2; ++mt) {
            const int row = (w * 2 + mt) * 16 + lr;
            a[mt] = *(const bf16x8*)(xbase + ((row * 128 + kk * 64 + lg * 16) ^ ((row & 7) << 4)));
        }
#pragma unroll
        for (int nt = 0; nt < 8; ++nt)
            b[nt] = *(const bf16x8*)(wd_bf + (nt * 16 + lr) * IN_D + kk * 32 + lg * 8);
#pragma unroll
        for (int mt = 0; mt < 2; ++mt)
#pragma unroll
            for (int nt = 0; nt < 8; ++nt)
                acc[mt][nt] = __builtin_amdgcn_mfma_f32_16x16x32_bf16(a[mt], b[nt], acc[mt][nt], 0, 0, 0);
    }
#pragma unroll
    for (int nt = 0; nt < 8; ++nt) {
        const float bj = bd[nt * 16 + lr];
        const int col2 = (nt * 16 + lr) * 2;
#pragma unroll
        for (int mt = 0; mt < 2; ++mt)
#pragma unroll
            for (int r = 0; r < 4; ++r) {
                const int row = (w * 2 + mt) * 16 + lg * 4 + r;
                const float v = fmaxf(acc[mt][nt][r] + bj, 0.f);
                *(ushort_t*)(dbase + ((row * 256 + col2) ^ ((row & 7) << 4))) = f2bf(v);
            }
    }
    __syncthreads();

#pragma unroll
    for (int mat = 0; mat < 2; ++mat) {
        const ushort_t* wm = mat ? wihb_bf : wihf_bf;
        const float* bs = mat ? bsb : bsf;
        ushort_t* outp = mat ? preB : preF;

        f32x4 acc2[2][8];
#pragma unroll
        for (int mt = 0; mt < 2; ++mt)
#pragma unroll
            for (int nt = 0; nt < 8; ++nt) acc2[mt][nt] = (f32x4){0.f, 0.f, 0.f, 0.f};

        for (int kk = 0; kk < 4; ++kk) {
            bf16x8 a[2], b[8];
#pragma unroll
            for (int mt = 0; mt < 2; ++mt) {
                const int row = (w * 2 + mt) * 16 + lr;
                a[mt] = *(const bf16x8*)(dbase + ((row * 256 + kk * 64 + lg * 16) ^ ((row & 7) << 4)));
            }
#pragma unroll
            for (int nt = 0; nt < 8; ++nt)
                b[nt] = *(const bf16x8*)(wm + (nt * 16 + lr) * HD + kk * 32 + lg * 8);
#pragma unroll
            for (int mt = 0; mt < 2; ++mt)
#pragma unroll
                for (int nt = 0; nt < 8; ++nt)
                    acc2[mt][nt] = __builtin_amdgcn_mfma_f32_16x16x32_bf16(a[mt], b[nt], acc2[mt][nt], 0, 0, 0);
        }
        float bsv[8];
#pragma unroll
        for (int nt = 0; nt < 8; ++nt) bsv[nt] = bs[nt * 16 + lr];
#pragma unroll
        for (int mt = 0; mt < 2; ++mt)
#pragma unroll
            for (int r = 0; r < 4; ++r) {
                const unsigned m = (unsigned)(m0 + (w * 2 + mt) * 16 + lg * 4 + r);
                const unsigned s = m / TT, t = m % TT;
                ushort_t* rowp = outp + ((size_t)t * BB + s) * HD;
#pragma unroll
                for (int nt = 0; nt < 8; ++nt)
                    rowp[nt * 16 + lr] = f2bf(acc2[mt][nt][r] + bsv[nt]);
            }
    }
}

// ---------------------------------------------------------------------------
// rnn v4: swapped-operand single-wave recurrence.
// 64 blocks x 64 threads; block = (16 samples, 1 dir). One wave owns the
// whole chain: A-frags = w_hh (128 VGPR, resident), B-frags = h^T via a
// wave-private 4KB LDS slab (no barriers). D cols = samples.
// pre[t] loaded to regs depth-2 (named pA/pB, 2-step unrolled, clamped addr).
// Head dot fused: h never goes to HBM. dotP layout [dir][s][t].
// ---------------------------------------------------------------------------
__global__ __launch_bounds__(64) void rnn_kernel(
    const ushort_t* __restrict__ preF, const ushort_t* __restrict__ preB,
    const ushort_t* __restrict__ whhF, const ushort_t* __restrict__ whhB,
    const float* __restrict__ fcw, const int* __restrict__ norder,
    float* __restrict__ dotP)
{
    __shared__ char hlds[4096];  // [16 s][128 j] bf16, XOR-swizzled
    const int bid = blockIdx.x;
    const int dir = bid & 1;
    const int s0 = (bid >> 1) * 16;
    const ushort_t* __restrict__ pre = dir ? preB : preF;
    const ushort_t* __restrict__ whh = dir ? whhB : whhF;

    const int l = threadIdx.x & 63;
    const int lr = l & 15, lg = l >> 4;

    // w_hh as A-fragments: A[row=j_out][k=j_in]; row on lr, k = kk*32+lg*8
    bf16x8 Afrag[8][4];
#pragma unroll
    for (int jt = 0; jt < 8; ++jt)
#pragma unroll
        for (int kk = 0; kk < 4; ++kk)
            Afrag[jt][kk] = *(const bf16x8*)(whh + (size_t)(jt * 16 + lr) * HD + kk * 32 + lg * 8);

    // head weights (D-layout: lane lr = sample, j = jt*16+lg*4+r)
    const int n = norder[s0 + lr];
    const float* wrow = fcw + (size_t)n * CD + HS + dir * HD;
    float wgv[8][4];
#pragma unroll
    for (int jt = 0; jt < 8; ++jt)
#pragma unroll
        for (int r = 0; r < 4; ++r)
            wgv[jt][r] = wrow[jt * 16 + lg * 4 + r];

    float* dout = dotP + (size_t)dir * BB * TT;

    // zero h slab (h_prev = 0 at step 0)
#pragma unroll
    for (int i = 0; i < 4; ++i)
        *(float4*)(hlds + l * 64 + i * 16) = (float4){0.f, 0.f, 0.f, 0.f};
    __syncthreads();

    const int dt = dir ? -1 : 1;
    const int t0 = dir ? (TT - 1) : 0;
    const size_t lane_off = (size_t)(s0 + lr) * HD + lg * 4;  // elements into a t-slab

    // depth-2 register prefetch of pre (4 bf16 per b64, 8 per step)
    uint2 pA[8], pB[8];
#pragma unroll
    for (int jt = 0; jt < 8; ++jt)
        pA[jt] = *(const uint2*)(pre + (size_t)t0 * (BB * HD) + lane_off + jt * 16);
#pragma unroll
    for (int jt = 0; jt < 8; ++jt)
        pB[jt] = *(const uint2*)(pre + (size_t)(t0 + dt) * (BB * HD) + lane_off + jt * 16);

    // LDS byte offsets (write D-layout b64, read B-layout b128), swizzled
    int wr_off[8];
#pragma unroll
    for (int jt = 0; jt < 8; ++jt)
        wr_off[jt] = (lr * 256 + jt * 32 + lg * 8) ^ ((lr & 7) << 4);
    int rd_off[4];
#pragma unroll
    for (int kk = 0; kk < 4; ++kk)
        rd_off[kk] = (lr * 256 + kk * 64 + lg * 16) ^ ((lr & 7) << 4);

    int t = t0;

#define RNN_STEP(P)                                                            \
    {                                                                          \
        bf16x8 Bfrag[4];                                                       \
        _Pragma("unroll")                                                      \
        for (int kk = 0; kk < 4; ++kk)                                         \
            Bfrag[kk] = *(const bf16x8*)(hlds + rd_off[kk]);                   \
        f32x4 acc[8];                                                          \
        _Pragma("unroll")                                                      \
        for (int jt = 0; jt < 8; ++jt) {                                       \
            acc[jt] = (f32x4){0.f, 0.f, 0.f, 0.f};                             \
            _Pragma("unroll")                                                  \
            for (int kk = 0; kk < 4; ++kk)                                     \
                acc[jt] = __builtin_amdgcn_mfma_f32_16x16x32_bf16(             \
                    Afrag[jt][kk], Bfrag[kk], acc[jt], 0, 0, 0);               \
        }                                                                      \
        float dacc = 0.f;                                                      \
        _Pragma("unroll")                                                      \
        for (int jt = 0; jt < 8; ++jt) {                                       \
            const float p0 = __builtin_bit_cast(float, (unsigned)(P[jt].x << 16));          \
            const float p1 = __builtin_bit_cast(float, (unsigned)(P[jt].x & 0xffff0000u));  \
            const float p2 = __builtin_bit_cast(float, (unsigned)(P[jt].y << 16));          \
            const float p3 = __builtin_bit_cast(float, (unsigned)(P[jt].y & 0xffff0000u));  \
            const float v0 = fmaxf(acc[jt][0] + p0, 0.f);                      \
            const float v1 = fmaxf(acc[jt][1] + p1, 0.f);                      \
            const float v2 = fmaxf(acc[jt][2] + p2, 0.f);                      \
            const float v3 = fmaxf(acc[jt][3] + p3, 0.f);                      \
            dacc = fmaf(v0, wgv[jt][0], dacc);                                 \
            dacc = fmaf(v1, wgv[jt][1], dacc);                                 \
            dacc = fmaf(v2, wgv[jt][2], dacc);                                 \
            dacc = fmaf(v3, wgv[jt][3], dacc);                                 \
            uint2 hw;                                                          \
            hw.x = ((unsigned)f2bf(v1) << 16) | (unsigned)f2bf(v0);            \
            hw.y = ((unsigned)f2bf(v3) << 16) | (unsigned)f2bf(v2);            \
            *(uint2*)(hlds + wr_off[jt]) = hw;                                 \
        }                                                                      \
        dacc += __shfl_xor(dacc, 16);                                          \
        dacc += __shfl_xor(dacc, 32);                                          \
        if (lg == 0) dout[(size_t)(s0 + lr) * TT + t] = dacc;                  \
        const int tp = t + 2 * dt;                                             \
        const int tc = tp < 0 ? 0 : (tp >= TT ? TT - 1 : tp);                  \
        const ushort_t* pb = pre + (size_t)tc * (BB * HD) + lane_off;          \
        _Pragma("unroll")                                                      \
        for (int jt = 0; jt < 8; ++jt) P[jt] = *(const uint2*)(pb + jt * 16);  \
        t += dt;                                                               \
    }

    for (int it = 0; it < TT / 2; ++it) {
        RNN_STEP(pA);
        RNN_STEP(pB);
    }
#undef RNN_STEP
}

// ---------------------------------------------------------------------------
// final: out[s*T+t] = relu(ds[s] + dotF[s][t] + dotB[s][t]) — fully coalesced.
// ---------------------------------------------------------------------------
__global__ __launch_bounds__(256) void final_kernel(
    const float* __restrict__ ds, const float* __restrict__ dotP,
    float* __restrict__ out)
{
    const int idx = blockIdx.x * 256 + threadIdx.x;  // < 153600 exactly
    const int s = idx / TT;
    out[idx] = fmaxf(ds[s] + dotP[idx] + dotP[BB * TT + idx], 0.f);
}

// ---------------------------------------------------------------------------
extern "C" void kernel_launch(void* const* d_in, const int* in_sizes, int n_in,
                              void* d_out, int out_size, void* d_ws, size_t ws_size,
                              hipStream_t stream)
{
    const float* x_static = (const float*)d_in[0];
    const float* x_dyn    = (const float*)d_in[1];
    const int*   norder   = (const int*)d_in[2];
    const float* w_s1 = (const float*)d_in[3];  const float* b_s1 = (const float*)d_in[4];
    const float* w_s2 = (const float*)d_in[5];  const float* b_s2 = (const float*)d_in[6];
    const float* w_d  = (const float*)d_in[7];  const float* b_d  = (const float*)d_in[8];
    const float* w_ih_f = (const float*)d_in[9];  const float* w_hh_f = (const float*)d_in[10];
    const float* b_ih_f = (const float*)d_in[11]; const float* b_hh_f = (const float*)d_in[12];
    const float* w_ih_b = (const float*)d_in[13]; const float* w_hh_b = (const float*)d_in[14];
    const float* b_ih_b = (const float*)d_in[15]; const float* b_hh_b = (const float*)d_in[16];
    const float* fc_w = (const float*)d_in[17];  const float* fc_b = (const float*)d_in[18];
    float* out = (float*)d_out;

    const size_t PRE_BYTES = (size_t)BB * TT * HD * sizeof(ushort_t);  // 39,321,600
    char* p = (char*)d_ws;
    ushort_t* preF    = (ushort_t*)p;
    ushort_t* preB    = (ushort_t*)(p + PRE_BYTES);
    char* q = p + 2 * PRE_BYTES;
    ushort_t* wd_bf   = (ushort_t*)q;               q += 16384 * sizeof(ushort_t);
    ushort_t* wihf_bf = (ushort_t*)q;               q += 16384 * sizeof(ushort_t);
    ushort_t* wihb_bf = (ushort_t*)q;               q += 16384 * sizeof(ushort_t);
    ushort_t* whhf_bf = (ushort_t*)q;               q += 16384 * sizeof(ushort_t);
    ushort_t* whhb_bf = (ushort_t*)q;               q += 16384 * sizeof(ushort_t);
    float* bsf = (float*)q;                         q += 256 * sizeof(float);
    float* bsb = (float*)q;                         q += 256 * sizeof(float);
    float* ds  = (float*)q;                         q += 512 * sizeof(float);
    float* dotP = (float*)q;                        // [2][512][300] f32

    prep_kernel<<<64, 256, 0, stream>>>(w_d, w_ih_f, w_ih_b, w_hh_f, w_hh_b,
                                        b_ih_f, b_hh_f, b_ih_b, b_hh_b,
                                        wd_bf, wihf_bf, wihb_bf, whhf_bf, whhb_bf, bsf, bsb);
    static_head_kernel<<<BB, 256, 0, stream>>>(x_static, norder, w_s1, b_s1, w_s2, b_s2,
                                               fc_w, fc_b, ds);
    proj_kernel<<<(BB * TT) / 128, 256, 0, stream>>>(x_dyn, wd_bf, b_d, wihf_bf, wihb_bf,
                                                     bsf, bsb, preF, preB);
    rnn_kernel<<<64, 64, 0, stream>>>(preF, preB, whhf_bf, whhb_bf, fc_w, norder, dotP);
    final_kernel<<<(BB * TT) / 256, 256, 0, stream>>>(ds, dotP, out);
}

// Round 5
// 345.536 us; speedup vs baseline: 1.0511x; 1.0511x over previous
//
#include <hip/hip_runtime.h>
#include <hip/hip_bf16.h>

#define BB 512
#define TT 300
#define IN_S 128
#define IN_D 64
#define HS 256
#define HD 128
#define CD 512  // 2*HD + HS

typedef __attribute__((ext_vector_type(8))) short bf16x8;
typedef __attribute__((ext_vector_type(4))) float f32x4;
typedef __attribute__((ext_vector_type(4))) unsigned uint4_t;
typedef unsigned short ushort_t;

static __device__ __forceinline__ ushort_t f2bf(float x) {
    unsigned u = __builtin_bit_cast(unsigned, x);
    unsigned r = (u + 0x7FFFu + ((u >> 16) & 1u)) >> 16;  // RNE
    return (ushort_t)r;
}
static __device__ __forceinline__ float bflo(unsigned u) {
    return __builtin_bit_cast(float, u << 16);
}
static __device__ __forceinline__ float bfhi(unsigned u) {
    return __builtin_bit_cast(float, u & 0xffff0000u);
}
static __device__ __forceinline__ unsigned cvt_pk(float lo, float hi) {
    unsigned r;
    asm("v_cvt_pk_bf16_f32 %0, %1, %2" : "=v"(r) : "v"(lo), "v"(hi));
    return r;
}

// ---------------------------------------------------------------------------
// prep: f32 weights -> bf16 workspace copies; fused RNN bias sums.
// ---------------------------------------------------------------------------
__global__ __launch_bounds__(256) void prep_kernel(
    const float* __restrict__ wd, const float* __restrict__ wihf, const float* __restrict__ wihb,
    const float* __restrict__ whhf, const float* __restrict__ whhb,
    const float* __restrict__ bif, const float* __restrict__ bhf,
    const float* __restrict__ bib, const float* __restrict__ bhb,
    ushort_t* __restrict__ wd_bf, ushort_t* __restrict__ wihf_bf, ushort_t* __restrict__ wihb_bf,
    ushort_t* __restrict__ whhf_bf, ushort_t* __restrict__ whhb_bf,
    float* __restrict__ bsf, float* __restrict__ bsb)
{
    const int i = blockIdx.x * 256 + threadIdx.x;  // < 16384
    if (i < HD * IN_D) wd_bf[i] = f2bf(wd[i]);
    wihf_bf[i] = f2bf(wihf[i]);
    wihb_bf[i] = f2bf(wihb[i]);
    whhf_bf[i] = f2bf(whhf[i]);
    whhb_bf[i] = f2bf(whhb[i]);
    if (i < HD) { bsf[i] = bif[i] + bhf[i]; bsb[i] = bib[i] + bhb[i]; }
}

// ---------------------------------------------------------------------------
// Kernel A (validated r0): static MLP + static head dot.
// ---------------------------------------------------------------------------
__global__ __launch_bounds__(256) void static_head_kernel(
    const float* __restrict__ xs, const int* __restrict__ norder,
    const float* __restrict__ w1, const float* __restrict__ b1,
    const float* __restrict__ w2, const float* __restrict__ b2,
    const float* __restrict__ fcw, const float* __restrict__ fcb,
    float* __restrict__ ds)
{
    __shared__ float xb[IN_S];
    __shared__ float s1[HS];
    __shared__ float red[4];
    const int b = blockIdx.x, tid = threadIdx.x;
    if (tid < IN_S) xb[tid] = xs[(size_t)b * IN_S + tid];
    __syncthreads();

    float a0 = 0.f, a1 = 0.f, a2 = 0.f, a3 = 0.f;
    {
        const float4* wsrc = (const float4*)(w1 + (size_t)tid * IN_S);
        const float4* x4 = (const float4*)xb;
#pragma unroll
        for (int i = 0; i < IN_S / 4; ++i) {
            float4 w = wsrc[i], x = x4[i];
            a0 = fmaf(w.x, x.x, a0); a1 = fmaf(w.y, x.y, a1);
            a2 = fmaf(w.z, x.z, a2); a3 = fmaf(w.w, x.w, a3);
        }
    }
    s1[tid] = fmaxf(b1[tid] + ((a0 + a1) + (a2 + a3)), 0.f);
    __syncthreads();

    a0 = a1 = a2 = a3 = 0.f;
    {
        const float4* wsrc = (const float4*)(w2 + (size_t)tid * HS);
        const float4* x4 = (const float4*)s1;
#pragma unroll
        for (int i = 0; i < HS / 4; ++i) {
            float4 w = wsrc[i], x = x4[i];
            a0 = fmaf(w.x, x.x, a0); a1 = fmaf(w.y, x.y, a1);
            a2 = fmaf(w.z, x.z, a2); a3 = fmaf(w.w, x.w, a3);
        }
    }
    float s2 = fmaxf(b2[tid] + ((a0 + a1) + (a2 + a3)), 0.f);

    const int n = norder[b];
    float p = s2 * fcw[(size_t)n * CD + tid];
#pragma unroll
    for (int o = 32; o >= 1; o >>= 1) p += __shfl_down(p, o);
    if ((tid & 63) == 0) red[tid >> 6] = p;
    __syncthreads();
    if (tid == 0) ds[b] = red[0] + red[1] + red[2] + red[3] + fcb[n];
}

// ---------------------------------------------------------------------------
// proj (validated r2, unchanged): MFMA bf16 projection + RNN input precompute.
// ---------------------------------------------------------------------------
__global__ __launch_bounds__(256) void proj_kernel(
    const float* __restrict__ xd, const ushort_t* __restrict__ wd_bf,
    const float* __restrict__ bd,
    const ushort_t* __restrict__ wihf_bf, const ushort_t* __restrict__ wihb_bf,
    const float* __restrict__ bsf, const float* __restrict__ bsb,
    ushort_t* __restrict__ preF, ushort_t* __restrict__ preB)
{
    __shared__ char lds[49152];
    char* dbase = lds;
    char* xbase = lds + 32768;
    const int tid = threadIdx.x;
    const int m0 = blockIdx.x * 128;

    {
        const int row = tid >> 1, half = tid & 1;
        const int swz = (row & 7) << 4;
        const float4* src = (const float4*)(xd + (size_t)(m0 + row) * IN_D + half * 32);
#pragma unroll
        for (int i = 0; i < 4; ++i) {
            float4 a = src[2 * i], b = src[2 * i + 1];
            bf16x8 v;
            v[0] = (short)f2bf(a.x); v[1] = (short)f2bf(a.y);
            v[2] = (short)f2bf(a.z); v[3] = (short)f2bf(a.w);
            v[4] = (short)f2bf(b.x); v[5] = (short)f2bf(b.y);
            v[6] = (short)f2bf(b.z); v[7] = (short)f2bf(b.w);
            *(bf16x8*)(xbase + ((row * 128 + half * 64 + i * 16) ^ swz)) = v;
        }
    }
    __syncthreads();

    const int w = tid >> 6, l = tid & 63;
    const int lr = l & 15, lg = l >> 4;

    f32x4 acc[2][8];
#pragma unroll
    for (int mt = 0; mt < 2; ++mt)
#pragma unroll
        for (int nt = 0; nt < 8; ++nt) acc[mt][nt] = (f32x4){0.f, 0.f, 0.f, 0.f};

    for (int kk = 0; kk < 2; ++kk) {
        bf16x8 a[2], b[8];
#pragma unroll
        for (int mt = 0; mt < 2; ++mt) {
            const int row = (w * 2 + mt) * 16 + lr;
            a[mt] = *(const bf16x8*)(xbase + ((row * 128 + kk * 64 + lg * 16) ^ ((row & 7) << 4)));
        }
#pragma unroll
        for (int nt = 0; nt < 8; ++nt)
            b[nt] = *(const bf16x8*)(wd_bf + (nt * 16 + lr) * IN_D + kk * 32 + lg * 8);
#pragma unroll
        for (int mt = 0; mt < 2; ++mt)
#pragma unroll
            for (int nt = 0; nt < 8; ++nt)
                acc[mt][nt] = __builtin_amdgcn_mfma_f32_16x16x32_bf16(a[mt], b[nt], acc[mt][nt], 0, 0, 0);
    }
#pragma unroll
    for (int nt = 0; nt < 8; ++nt) {
        const float bj = bd[nt * 16 + lr];
        const int col2 = (nt * 16 + lr) * 2;
#pragma unroll
        for (int mt = 0; mt < 2; ++mt)
#pragma unroll
            for (int r = 0; r < 4; ++r) {
                const int row = (w * 2 + mt) * 16 + lg * 4 + r;
                const float v = fmaxf(acc[mt][nt][r] + bj, 0.f);
                *(ushort_t*)(dbase + ((row * 256 + col2) ^ ((row & 7) << 4))) = f2bf(v);
            }
    }
    __syncthreads();

#pragma unroll
    for (int mat = 0; mat < 2; ++mat) {
        const ushort_t* wm = mat ? wihb_bf : wihf_bf;
        const float* bs = mat ? bsb : bsf;
        ushort_t* outp = mat ? preB : preF;

        f32x4 acc2[2][8];
#pragma unroll
        for (int mt = 0; mt < 2; ++mt)
#pragma unroll
            for (int nt = 0; nt < 8; ++nt) acc2[mt][nt] = (f32x4){0.f, 0.f, 0.f, 0.f};

        for (int kk = 0; kk < 4; ++kk) {
            bf16x8 a[2], b[8];
#pragma unroll
            for (int mt = 0; mt < 2; ++mt) {
                const int row = (w * 2 + mt) * 16 + lr;
                a[mt] = *(const bf16x8*)(dbase + ((row * 256 + kk * 64 + lg * 16) ^ ((row & 7) << 4)));
            }
#pragma unroll
            for (int nt = 0; nt < 8; ++nt)
                b[nt] = *(const bf16x8*)(wm + (nt * 16 + lr) * HD + kk * 32 + lg * 8);
#pragma unroll
            for (int mt = 0; mt < 2; ++mt)
#pragma unroll
                for (int nt = 0; nt < 8; ++nt)
                    acc2[mt][nt] = __builtin_amdgcn_mfma_f32_16x16x32_bf16(a[mt], b[nt], acc2[mt][nt], 0, 0, 0);
        }
        float bsv[8];
#pragma unroll
        for (int nt = 0; nt < 8; ++nt) bsv[nt] = bs[nt * 16 + lr];
#pragma unroll
        for (int mt = 0; mt < 2; ++mt)
#pragma unroll
            for (int r = 0; r < 4; ++r) {
                const unsigned m = (unsigned)(m0 + (w * 2 + mt) * 16 + lg * 4 + r);
                const unsigned s = m / TT, t = m % TT;
                ushort_t* rowp = outp + ((size_t)t * BB + s) * HD;
#pragma unroll
                for (int nt = 0; nt < 8; ++nt)
                    rowp[nt * 16 + lr] = f2bf(acc2[mt][nt][r] + bsv[nt]);
            }
    }
}

// ---------------------------------------------------------------------------
// rnn v5: fully in-register recurrence. 64 blocks x 1 wave (16 samples, 1 dir).
// A-rows of w_hh are PERMUTED so that D's lane layout IS the next step's
// B-fragment layout: pi(jt,m) = (jt&3)*32 + (m>>2)*8 + (jt>>2)*4 + (m&3).
// Then Bfrag[kk] = {pack(v[kk][0],v[kk][1]), pack(v[kk][2],v[kk][3]),
//                   pack(v[kk+4][0],v[kk+4][1]), pack(v[kk+4][2],v[kk+4][3])}
// -- all lane-local. No LDS, no shuffles, no barriers in the loop.
// pre[t] initializes the MFMA C operand (depth-2 register prefetch).
// Head dot fused on f32 values; h never touches HBM.
// ---------------------------------------------------------------------------
__global__ __launch_bounds__(64, 1) void rnn_kernel(
    const ushort_t* __restrict__ preF, const ushort_t* __restrict__ preB,
    const ushort_t* __restrict__ whhF, const ushort_t* __restrict__ whhB,
    const float* __restrict__ fcw, const int* __restrict__ norder,
    float* __restrict__ dotP)
{
    const int bid = blockIdx.x;
    const int dir = bid & 1;
    const int s0 = (bid >> 1) * 16;
    const ushort_t* __restrict__ pre = dir ? preB : preF;
    const ushort_t* __restrict__ whh = dir ? whhB : whhF;

    const int l = threadIdx.x & 63;
    const int lr = l & 15, lg = l >> 4;

    // A fragments with permuted rows: tile jt, in-tile row m=lr -> whh row pi(jt,lr)
    bf16x8 Afrag[8][4];
#pragma unroll
    for (int jt = 0; jt < 8; ++jt) {
        const int row = (jt & 3) * 32 + (lr >> 2) * 8 + (jt >> 2) * 4 + (lr & 3);
#pragma unroll
        for (int kk = 0; kk < 4; ++kk)
            Afrag[jt][kk] = *(const bf16x8*)(whh + (size_t)row * HD + kk * 32 + lg * 8);
    }

    // head weights at the D positions this thread owns: j = pi(jt, lg*4+r)
    const int n = norder[s0 + lr];
    const float* wrow = fcw + (size_t)n * CD + HS + dir * HD;
    float wgv[8][4];
#pragma unroll
    for (int jt = 0; jt < 8; ++jt) {
        const int jb = (jt & 3) * 32 + lg * 8 + (jt >> 2) * 4;
#pragma unroll
        for (int r = 0; r < 4; ++r)
            wgv[jt][r] = wrow[jb + r];
    }

    float* dout = dotP + (size_t)dir * BB * TT + (size_t)(s0 + lr) * TT;

    const int dt = dir ? -1 : 1;
    const int t0 = dir ? (TT - 1) : 0;
    const int base_off = (s0 + lr) * HD + lg * 8;  // + (jt&3)*32 + (jt>>2)*4

    // packed h state (= next B fragments); h_{-1} = 0
    unsigned BQ[4][4];
#pragma unroll
    for (int kk = 0; kk < 4; ++kk)
#pragma unroll
        for (int q = 0; q < 4; ++q) BQ[kk][q] = 0u;

    // depth-2 register prefetch of pre (C operand), permuted-j addressing
    uint2 pA[8], pB[8];
    {
        const ushort_t* p0 = pre + (size_t)t0 * (BB * HD) + base_off;
        const ushort_t* p1 = pre + (size_t)(t0 + dt) * (BB * HD) + base_off;
#pragma unroll
        for (int jt = 0; jt < 8; ++jt) {
            const int jo = (jt & 3) * 32 + (jt >> 2) * 4;
            pA[jt] = *(const uint2*)(p0 + jo);
            pB[jt] = *(const uint2*)(p1 + jo);
        }
    }

    int t = t0;

#define RNN_STEP(P)                                                            \
    {                                                                          \
        f32x4 acc[8];                                                          \
        _Pragma("unroll")                                                      \
        for (int jt = 0; jt < 8; ++jt) {                                       \
            acc[jt][0] = bflo(P[jt].x); acc[jt][1] = bfhi(P[jt].x);            \
            acc[jt][2] = bflo(P[jt].y); acc[jt][3] = bfhi(P[jt].y);            \
        }                                                                      \
        _Pragma("unroll")                                                      \
        for (int kk = 0; kk < 4; ++kk) {                                       \
            const bf16x8 bq = __builtin_bit_cast(bf16x8,                       \
                (uint4_t){BQ[kk][0], BQ[kk][1], BQ[kk][2], BQ[kk][3]});        \
            _Pragma("unroll")                                                  \
            for (int jt = 0; jt < 8; ++jt)                                     \
                acc[jt] = __builtin_amdgcn_mfma_f32_16x16x32_bf16(             \
                    Afrag[jt][kk], bq, acc[jt], 0, 0, 0);                      \
        }                                                                      \
        float dacc = 0.f;                                                      \
        _Pragma("unroll")                                                      \
        for (int jt = 0; jt < 8; ++jt) {                                       \
            const float v0 = fmaxf(acc[jt][0], 0.f);                           \
            const float v1 = fmaxf(acc[jt][1], 0.f);                           \
            const float v2 = fmaxf(acc[jt][2], 0.f);                           \
            const float v3 = fmaxf(acc[jt][3], 0.f);                           \
            dacc = fmaf(v0, wgv[jt][0], dacc);                                 \
            dacc = fmaf(v1, wgv[jt][1], dacc);                                 \
            dacc = fmaf(v2, wgv[jt][2], dacc);                                 \
            dacc = fmaf(v3, wgv[jt][3], dacc);                                 \
            const unsigned q01 = cvt_pk(v0, v1);                               \
            const unsigned q23 = cvt_pk(v2, v3);                               \
            if (jt < 4) { BQ[jt][0] = q01; BQ[jt][1] = q23; }                  \
            else        { BQ[jt - 4][2] = q01; BQ[jt - 4][3] = q23; }          \
        }                                                                      \
        dacc += __shfl_xor(dacc, 16);                                          \
        dacc += __shfl_xor(dacc, 32);                                          \
        if (lg == 0) dout[t] = dacc;                                           \
        const int tp = t + 2 * dt;                                             \
        const int tc = tp < 0 ? 0 : (tp >= TT ? TT - 1 : tp);                  \
        const ushort_t* pb = pre + (size_t)tc * (BB * HD) + base_off;          \
        _Pragma("unroll")                                                      \
        for (int jt = 0; jt < 8; ++jt)                                         \
            P[jt] = *(const uint2*)(pb + ((jt & 3) * 32 + (jt >> 2) * 4));     \
        t += dt;                                                               \
    }

    for (int it = 0; it < TT / 2; ++it) {
        RNN_STEP(pA);
        RNN_STEP(pB);
    }
#undef RNN_STEP
}

// ---------------------------------------------------------------------------
// final: out[s*T+t] = relu(ds[s] + dotF[s][t] + dotB[s][t]) — fully coalesced.
// ---------------------------------------------------------------------------
__global__ __launch_bounds__(256) void final_kernel(
    const float* __restrict__ ds, const float* __restrict__ dotP,
    float* __restrict__ out)
{
    const int idx = blockIdx.x * 256 + threadIdx.x;  // < 153600 exactly
    const int s = idx / TT;
    out[idx] = fmaxf(ds[s] + dotP[idx] + dotP[BB * TT + idx], 0.f);
}

// ---------------------------------------------------------------------------
extern "C" void kernel_launch(void* const* d_in, const int* in_sizes, int n_in,
                              void* d_out, int out_size, void* d_ws, size_t ws_size,
                              hipStream_t stream)
{
    const float* x_static = (const float*)d_in[0];
    const float* x_dyn    = (const float*)d_in[1];
    const int*   norder   = (const int*)d_in[2];
    const float* w_s1 = (const float*)d_in[3];  const float* b_s1 = (const float*)d_in[4];
    const float* w_s2 = (const float*)d_in[5];  const float* b_s2 = (const float*)d_in[6];
    const float* w_d  = (const float*)d_in[7];  const float* b_d  = (const float*)d_in[8];
    const float* w_ih_f = (const float*)d_in[9];  const float* w_hh_f = (const float*)d_in[10];
    const float* b_ih_f = (const float*)d_in[11]; const float* b_hh_f = (const float*)d_in[12];
    const float* w_ih_b = (const float*)d_in[13]; const float* w_hh_b = (const float*)d_in[14];
    const float* b_ih_b = (const float*)d_in[15]; const float* b_hh_b = (const float*)d_in[16];
    const float* fc_w = (const float*)d_in[17];  const float* fc_b = (const float*)d_in[18];
    float* out = (float*)d_out;

    const size_t PRE_BYTES = (size_t)BB * TT * HD * sizeof(ushort_t);  // 39,321,600
    char* p = (char*)d_ws;
    ushort_t* preF    = (ushort_t*)p;
    ushort_t* preB    = (ushort_t*)(p + PRE_BYTES);
    char* q = p + 2 * PRE_BYTES;
    ushort_t* wd_bf   = (ushort_t*)q;               q += 16384 * sizeof(ushort_t);
    ushort_t* wihf_bf = (ushort_t*)q;               q += 16384 * sizeof(ushort_t);
    ushort_t* wihb_bf = (ushort_t*)q;               q += 16384 * sizeof(ushort_t);
    ushort_t* whhf_bf = (ushort_t*)q;               q += 16384 * sizeof(ushort_t);
    ushort_t* whhb_bf = (ushort_t*)q;               q += 16384 * sizeof(ushort_t);
    float* bsf = (float*)q;                         q += 256 * sizeof(float);
    float* bsb = (float*)q;                         q += 256 * sizeof(float);
    float* ds  = (float*)q;                         q += 512 * sizeof(float);
    float* dotP = (float*)q;                        // [2][512][300] f32

    prep_kernel<<<64, 256, 0, stream>>>(w_d, w_ih_f, w_ih_b, w_hh_f, w_hh_b,
                                        b_ih_f, b_hh_f, b_ih_b, b_hh_b,
                                        wd_bf, wihf_bf, wihb_bf, whhf_bf, whhb_bf, bsf, bsb);
    static_head_kernel<<<BB, 256, 0, stream>>>(x_static, norder, w_s1, b_s1, w_s2, b_s2,
                                               fc_w, fc_b, ds);
    proj_kernel<<<(BB * TT) / 128, 256, 0, stream>>>(x_dyn, wd_bf, b_d, wihf_bf, wihb_bf,
                                                     bsf, bsb, preF, preB);
    rnn_kernel<<<64, 64, 0, stream>>>(preF, preB, whhf_bf, whhb_bf, fc_w, norder, dotP);
    final_kernel<<<(BB * TT) / 256, 256, 0, stream>>>(ds, dotP, out);
}

// Round 6
// 304.879 us; speedup vs baseline: 1.1913x; 1.1334x over previous
//
#include <hip/hip_runtime.h>
#include <hip/hip_bf16.h>

#define BB 512
#define TT 300
#define IN_S 128
#define IN_D 64
#define HS 256
#define HD 128
#define CD 512  // 2*HD + HS

typedef __attribute__((ext_vector_type(8))) short bf16x8;
typedef __attribute__((ext_vector_type(4))) float f32x4;
typedef __attribute__((ext_vector_type(4))) unsigned uint4_t;
typedef unsigned short ushort_t;

static __device__ __forceinline__ ushort_t f2bf(float x) {
    unsigned u = __builtin_bit_cast(unsigned, x);
    unsigned r = (u + 0x7FFFu + ((u >> 16) & 1u)) >> 16;  // RNE
    return (ushort_t)r;
}
static __device__ __forceinline__ float bflo(unsigned u) {
    return __builtin_bit_cast(float, u << 16);
}
static __device__ __forceinline__ float bfhi(unsigned u) {
    return __builtin_bit_cast(float, u & 0xffff0000u);
}
static __device__ __forceinline__ unsigned cvt_pk(float lo, float hi) {
    unsigned r;
    asm("v_cvt_pk_bf16_f32 %0, %1, %2" : "=v"(r) : "v"(lo), "v"(hi));
    return r;
}

// ---------------------------------------------------------------------------
// prep: f32 weights -> bf16 workspace copies; fused RNN bias sums.
// ---------------------------------------------------------------------------
__global__ __launch_bounds__(256) void prep_kernel(
    const float* __restrict__ wd, const float* __restrict__ wihf, const float* __restrict__ wihb,
    const float* __restrict__ whhf, const float* __restrict__ whhb,
    const float* __restrict__ bif, const float* __restrict__ bhf,
    const float* __restrict__ bib, const float* __restrict__ bhb,
    ushort_t* __restrict__ wd_bf, ushort_t* __restrict__ wihf_bf, ushort_t* __restrict__ wihb_bf,
    ushort_t* __restrict__ whhf_bf, ushort_t* __restrict__ whhb_bf,
    float* __restrict__ bsf, float* __restrict__ bsb)
{
    const int i = blockIdx.x * 256 + threadIdx.x;  // < 16384
    if (i < HD * IN_D) wd_bf[i] = f2bf(wd[i]);
    wihf_bf[i] = f2bf(wihf[i]);
    wihb_bf[i] = f2bf(wihb[i]);
    whhf_bf[i] = f2bf(whhf[i]);
    whhb_bf[i] = f2bf(whhb[i]);
    if (i < HD) { bsf[i] = bif[i] + bhf[i]; bsb[i] = bib[i] + bhb[i]; }
}

// ---------------------------------------------------------------------------
// Kernel A (validated r0): static MLP + static head dot.
// ---------------------------------------------------------------------------
__global__ __launch_bounds__(256) void static_head_kernel(
    const float* __restrict__ xs, const int* __restrict__ norder,
    const float* __restrict__ w1, const float* __restrict__ b1,
    const float* __restrict__ w2, const float* __restrict__ b2,
    const float* __restrict__ fcw, const float* __restrict__ fcb,
    float* __restrict__ ds)
{
    __shared__ float xb[IN_S];
    __shared__ float s1[HS];
    __shared__ float red[4];
    const int b = blockIdx.x, tid = threadIdx.x;
    if (tid < IN_S) xb[tid] = xs[(size_t)b * IN_S + tid];
    __syncthreads();

    float a0 = 0.f, a1 = 0.f, a2 = 0.f, a3 = 0.f;
    {
        const float4* wsrc = (const float4*)(w1 + (size_t)tid * IN_S);
        const float4* x4 = (const float4*)xb;
#pragma unroll
        for (int i = 0; i < IN_S / 4; ++i) {
            float4 w = wsrc[i], x = x4[i];
            a0 = fmaf(w.x, x.x, a0); a1 = fmaf(w.y, x.y, a1);
            a2 = fmaf(w.z, x.z, a2); a3 = fmaf(w.w, x.w, a3);
        }
    }
    s1[tid] = fmaxf(b1[tid] + ((a0 + a1) + (a2 + a3)), 0.f);
    __syncthreads();

    a0 = a1 = a2 = a3 = 0.f;
    {
        const float4* wsrc = (const float4*)(w2 + (size_t)tid * HS);
        const float4* x4 = (const float4*)s1;
#pragma unroll
        for (int i = 0; i < HS / 4; ++i) {
            float4 w = wsrc[i], x = x4[i];
            a0 = fmaf(w.x, x.x, a0); a1 = fmaf(w.y, x.y, a1);
            a2 = fmaf(w.z, x.z, a2); a3 = fmaf(w.w, x.w, a3);
        }
    }
    float s2 = fmaxf(b2[tid] + ((a0 + a1) + (a2 + a3)), 0.f);

    const int n = norder[b];
    float p = s2 * fcw[(size_t)n * CD + tid];
#pragma unroll
    for (int o = 32; o >= 1; o >>= 1) p += __shfl_down(p, o);
    if ((tid & 63) == 0) red[tid >> 6] = p;
    __syncthreads();
    if (tid == 0) ds[b] = red[0] + red[1] + red[2] + red[3] + fcb[n];
}

// ---------------------------------------------------------------------------
// proj (validated r2, unchanged): MFMA bf16 projection + RNN input precompute.
// ---------------------------------------------------------------------------
__global__ __launch_bounds__(256) void proj_kernel(
    const float* __restrict__ xd, const ushort_t* __restrict__ wd_bf,
    const float* __restrict__ bd,
    const ushort_t* __restrict__ wihf_bf, const ushort_t* __restrict__ wihb_bf,
    const float* __restrict__ bsf, const float* __restrict__ bsb,
    ushort_t* __restrict__ preF, ushort_t* __restrict__ preB)
{
    __shared__ char lds[49152];
    char* dbase = lds;
    char* xbase = lds + 32768;
    const int tid = threadIdx.x;
    const int m0 = blockIdx.x * 128;

    {
        const int row = tid >> 1, half = tid & 1;
        const int swz = (row & 7) << 4;
        const float4* src = (const float4*)(xd + (size_t)(m0 + row) * IN_D + half * 32);
#pragma unroll
        for (int i = 0; i < 4; ++i) {
            float4 a = src[2 * i], b = src[2 * i + 1];
            bf16x8 v;
            v[0] = (short)f2bf(a.x); v[1] = (short)f2bf(a.y);
            v[2] = (short)f2bf(a.z); v[3] = (short)f2bf(a.w);
            v[4] = (short)f2bf(b.x); v[5] = (short)f2bf(b.y);
            v[6] = (short)f2bf(b.z); v[7] = (short)f2bf(b.w);
            *(bf16x8*)(xbase + ((row * 128 + half * 64 + i * 16) ^ swz)) = v;
        }
    }
    __syncthreads();

    const int w = tid >> 6, l = tid & 63;
    const int lr = l & 15, lg = l >> 4;

    f32x4 acc[2][8];
#pragma unroll
    for (int mt = 0; mt < 2; ++mt)
#pragma unroll
        for (int nt = 0; nt < 8; ++nt) acc[mt][nt] = (f32x4){0.f, 0.f, 0.f, 0.f};

    for (int kk = 0; kk < 2; ++kk) {
        bf16x8 a[2], b[8];
#pragma unroll
        for (int mt = 0; mt < 2; ++mt) {
            const int row = (w * 2 + mt) * 16 + lr;
            a[mt] = *(const bf16x8*)(xbase + ((row * 128 + kk * 64 + lg * 16) ^ ((row & 7) << 4)));
        }
#pragma unroll
        for (int nt = 0; nt < 8; ++nt)
            b[nt] = *(const bf16x8*)(wd_bf + (nt * 16 + lr) * IN_D + kk * 32 + lg * 8);
#pragma unroll
        for (int mt = 0; mt < 2; ++mt)
#pragma unroll
            for (int nt = 0; nt < 8; ++nt)
                acc[mt][nt] = __builtin_amdgcn_mfma_f32_16x16x32_bf16(a[mt], b[nt], acc[mt][nt], 0, 0, 0);
    }
#pragma unroll
    for (int nt = 0; nt < 8; ++nt) {
        const float bj = bd[nt * 16 + lr];
        const int col2 = (nt * 16 + lr) * 2;
#pragma unroll
        for (int mt = 0; mt < 2; ++mt)
#pragma unroll
            for (int r = 0; r < 4; ++r) {
                const int row = (w * 2 + mt) * 16 + lg * 4 + r;
                const float v = fmaxf(acc[mt][nt][r] + bj, 0.f);
                *(ushort_t*)(dbase + ((row * 256 + col2) ^ ((row & 7) << 4))) = f2bf(v);
            }
    }
    __syncthreads();

#pragma unroll
    for (int mat = 0; mat < 2; ++mat) {
        const ushort_t* wm = mat ? wihb_bf : wihf_bf;
        const float* bs = mat ? bsb : bsf;
        ushort_t* outp = mat ? preB : preF;

        f32x4 acc2[2][8];
#pragma unroll
        for (int mt = 0; mt < 2; ++mt)
#pragma unroll
            for (int nt = 0; nt < 8; ++nt) acc2[mt][nt] = (f32x4){0.f, 0.f, 0.f, 0.f};

        for (int kk = 0; kk < 4; ++kk) {
            bf16x8 a[2], b[8];
#pragma unroll
            for (int mt = 0; mt < 2; ++mt) {
                const int row = (w * 2 + mt) * 16 + lr;
                a[mt] = *(const bf16x8*)(dbase + ((row * 256 + kk * 64 + lg * 16) ^ ((row & 7) << 4)));
            }
#pragma unroll
            for (int nt = 0; nt < 8; ++nt)
                b[nt] = *(const bf16x8*)(wm + (nt * 16 + lr) * HD + kk * 32 + lg * 8);
#pragma unroll
            for (int mt = 0; mt < 2; ++mt)
#pragma unroll
                for (int nt = 0; nt < 8; ++nt)
                    acc2[mt][nt] = __builtin_amdgcn_mfma_f32_16x16x32_bf16(a[mt], b[nt], acc2[mt][nt], 0, 0, 0);
        }
        float bsv[8];
#pragma unroll
        for (int nt = 0; nt < 8; ++nt) bsv[nt] = bs[nt * 16 + lr];
#pragma unroll
        for (int mt = 0; mt < 2; ++mt)
#pragma unroll
            for (int r = 0; r < 4; ++r) {
                const unsigned m = (unsigned)(m0 + (w * 2 + mt) * 16 + lg * 4 + r);
                const unsigned s = m / TT, t = m % TT;
                ushort_t* rowp = outp + ((size_t)t * BB + s) * HD;
#pragma unroll
                for (int nt = 0; nt < 8; ++nt)
                    rowp[nt * 16 + lr] = f2bf(acc2[mt][nt][r] + bsv[nt]);
            }
    }
}

// ---------------------------------------------------------------------------
// rnn v6: in-register recurrence, minimal register footprint.
// 64 blocks x 1 wave (16 samples, 1 dir). A-rows of w_hh permuted:
// pi(jt,m) = (jt&3)*32 + (m>>2)*8 + (jt>>2)*4 + (m&3), so D's lane layout IS
// the next step's B-fragment layout (lane-local repack, no LDS/shuffle), AND
// the packed quad BQ[kk] is j-contiguous -> h stores/loads are dwordx4 in
// standard [t][s][j] layout. h written in-place over consumed pre[t].
// Head dot moved OUT (r2-validated dot_kernel) to cut 32 VGPR + serial chain.
// ---------------------------------------------------------------------------
__global__ __launch_bounds__(64, 1) void rnn_kernel(
    ushort_t* __restrict__ preF, ushort_t* __restrict__ preB,
    const ushort_t* __restrict__ whhF, const ushort_t* __restrict__ whhB)
{
    const int bid = blockIdx.x;
    const int dir = bid & 1;
    const int s0 = (bid >> 1) * 16;
    ushort_t* __restrict__ pre = dir ? preB : preF;
    const ushort_t* __restrict__ whh = dir ? whhB : whhF;

    const int l = threadIdx.x & 63;
    const int lr = l & 15, lg = l >> 4;

    // A fragments with permuted rows: tile jt, in-tile row m=lr -> whh row pi(jt,lr)
    bf16x8 Afrag[8][4];
#pragma unroll
    for (int jt = 0; jt < 8; ++jt) {
        const int row = (jt & 3) * 32 + (lr >> 2) * 8 + (jt >> 2) * 4 + (lr & 3);
#pragma unroll
        for (int kk = 0; kk < 4; ++kk)
            Afrag[jt][kk] = *(const bf16x8*)(whh + (size_t)row * HD + kk * 32 + lg * 8);
    }

    const int dt = dir ? -1 : 1;
    const int t0 = dir ? (TT - 1) : 0;
    const int base_off = (s0 + lr) * HD + lg * 8;  // + kk*32 covers j-quad pairs

    // packed h state (= next B fragments); h_{-1} = 0
    unsigned BQ[4][4];
#pragma unroll
    for (int kk = 0; kk < 4; ++kk)
#pragma unroll
        for (int q = 0; q < 4; ++q) BQ[kk][q] = 0u;

    // depth-2 register prefetch of pre (C operand): 4 x dwordx4 per buffer
    uint4_t pA[4], pB[4];
    {
        const ushort_t* p0 = pre + (size_t)t0 * (BB * HD) + base_off;
        const ushort_t* p1 = pre + (size_t)(t0 + dt) * (BB * HD) + base_off;
#pragma unroll
        for (int kk = 0; kk < 4; ++kk) {
            pA[kk] = *(const uint4_t*)(p0 + kk * 32);
            pB[kk] = *(const uint4_t*)(p1 + kk * 32);
        }
    }

    int t = t0;

#define RNN_STEP(P)                                                            \
    {                                                                          \
        f32x4 acc[8];                                                          \
        _Pragma("unroll")                                                      \
        for (int kk = 0; kk < 4; ++kk) {                                       \
            acc[kk][0] = bflo(P[kk].x);     acc[kk][1] = bfhi(P[kk].x);        \
            acc[kk][2] = bflo(P[kk].y);     acc[kk][3] = bfhi(P[kk].y);        \
            acc[kk + 4][0] = bflo(P[kk].z); acc[kk + 4][1] = bfhi(P[kk].z);    \
            acc[kk + 4][2] = bflo(P[kk].w); acc[kk + 4][3] = bfhi(P[kk].w);    \
        }                                                                      \
        _Pragma("unroll")                                                      \
        for (int kk = 0; kk < 4; ++kk) {                                       \
            const bf16x8 bq = __builtin_bit_cast(bf16x8,                       \
                (uint4_t){BQ[kk][0], BQ[kk][1], BQ[kk][2], BQ[kk][3]});        \
            _Pragma("unroll")                                                  \
            for (int jt = 0; jt < 8; ++jt)                                     \
                acc[jt] = __builtin_amdgcn_mfma_f32_16x16x32_bf16(             \
                    Afrag[jt][kk], bq, acc[jt], 0, 0, 0);                      \
        }                                                                      \
        _Pragma("unroll")                                                      \
        for (int jt = 0; jt < 8; ++jt) {                                       \
            const float v0 = fmaxf(acc[jt][0], 0.f);                           \
            const float v1 = fmaxf(acc[jt][1], 0.f);                           \
            const float v2 = fmaxf(acc[jt][2], 0.f);                           \
            const float v3 = fmaxf(acc[jt][3], 0.f);                           \
            const unsigned q01 = cvt_pk(v0, v1);                               \
            const unsigned q23 = cvt_pk(v2, v3);                               \
            if (jt < 4) { BQ[jt][0] = q01; BQ[jt][1] = q23; }                  \
            else        { BQ[jt - 4][2] = q01; BQ[jt - 4][3] = q23; }          \
        }                                                                      \
        {   /* store h (= BQ quads, j-contiguous) over consumed pre[t] */      \
            ushort_t* hb = pre + (size_t)t * (BB * HD) + base_off;             \
            _Pragma("unroll")                                                  \
            for (int kk = 0; kk < 4; ++kk)                                     \
                *(uint4_t*)(hb + kk * 32) =                                    \
                    (uint4_t){BQ[kk][0], BQ[kk][1], BQ[kk][2], BQ[kk][3]};     \
        }                                                                      \
        const int tp = t + 2 * dt;                                             \
        const int tc = tp < 0 ? 0 : (tp >= TT ? TT - 1 : tp);                  \
        const ushort_t* pb = pre + (size_t)tc * (BB * HD) + base_off;          \
        _Pragma("unroll")                                                      \
        for (int kk = 0; kk < 4; ++kk) P[kk] = *(const uint4_t*)(pb + kk * 32);\
        t += dt;                                                               \
    }

    for (int it = 0; it < TT / 2; ++it) {
        RNN_STEP(pA);
        RNN_STEP(pB);
    }
#undef RNN_STEP
}

// ---------------------------------------------------------------------------
// dot (validated r2): out[s*T+t] = relu(ds[s] + hf[t,s,:].wgf + hb[t,s,:].wgb)
// ---------------------------------------------------------------------------
__global__ __launch_bounds__(256) void dot_kernel(
    const ushort_t* __restrict__ hF, const ushort_t* __restrict__ hB,
    const float* __restrict__ fcw, const int* __restrict__ norder,
    const float* __restrict__ ds, float* __restrict__ out)
{
    const int gw = blockIdx.x * 4 + (threadIdx.x >> 6);  // < 2560
    const int s = gw / 5, chunk = gw % 5;
    const int l = threadIdx.x & 63, lr = l & 15, lg = l >> 4;
    const int n = norder[s];
    const float4* wf4 = (const float4*)(fcw + (size_t)n * CD + HS);
    const float4* wb4 = (const float4*)(fcw + (size_t)n * CD + HS + HD);
    const float4 wf0 = wf4[lr * 2], wf1 = wf4[lr * 2 + 1];
    const float4 wb0 = wb4[lr * 2], wb1 = wb4[lr * 2 + 1];
    const float dsv = ds[s];

    for (int it = 0; it < 15; ++it) {
        const int t = chunk * 60 + it * 4 + lg;
        const size_t off = ((size_t)t * BB + s) * HD + lr * 8;
        const bf16x8 hf = *(const bf16x8*)(hF + off);
        const bf16x8 hb = *(const bf16x8*)(hB + off);
        float a = 0.f;
        a = fmaf(bflo((unsigned)(ushort_t)hf[0]), wf0.x, a);
        a = fmaf(bflo((unsigned)(ushort_t)hf[1]), wf0.y, a);
        a = fmaf(bflo((unsigned)(ushort_t)hf[2]), wf0.z, a);
        a = fmaf(bflo((unsigned)(ushort_t)hf[3]), wf0.w, a);
        a = fmaf(bflo((unsigned)(ushort_t)hf[4]), wf1.x, a);
        a = fmaf(bflo((unsigned)(ushort_t)hf[5]), wf1.y, a);
        a = fmaf(bflo((unsigned)(ushort_t)hf[6]), wf1.z, a);
        a = fmaf(bflo((unsigned)(ushort_t)hf[7]), wf1.w, a);
        a = fmaf(bflo((unsigned)(ushort_t)hb[0]), wb0.x, a);
        a = fmaf(bflo((unsigned)(ushort_t)hb[1]), wb0.y, a);
        a = fmaf(bflo((unsigned)(ushort_t)hb[2]), wb0.z, a);
        a = fmaf(bflo((unsigned)(ushort_t)hb[3]), wb0.w, a);
        a = fmaf(bflo((unsigned)(ushort_t)hb[4]), wb1.x, a);
        a = fmaf(bflo((unsigned)(ushort_t)hb[5]), wb1.y, a);
        a = fmaf(bflo((unsigned)(ushort_t)hb[6]), wb1.z, a);
        a = fmaf(bflo((unsigned)(ushort_t)hb[7]), wb1.w, a);
#pragma unroll
        for (int o = 1; o < 16; o <<= 1) a += __shfl_xor(a, o);
        if (lr == 0) out[s * TT + t] = fmaxf(a + dsv, 0.f);
    }
}

// ---------------------------------------------------------------------------
extern "C" void kernel_launch(void* const* d_in, const int* in_sizes, int n_in,
                              void* d_out, int out_size, void* d_ws, size_t ws_size,
                              hipStream_t stream)
{
    const float* x_static = (const float*)d_in[0];
    const float* x_dyn    = (const float*)d_in[1];
    const int*   norder   = (const int*)d_in[2];
    const float* w_s1 = (const float*)d_in[3];  const float* b_s1 = (const float*)d_in[4];
    const float* w_s2 = (const float*)d_in[5];  const float* b_s2 = (const float*)d_in[6];
    const float* w_d  = (const float*)d_in[7];  const float* b_d  = (const float*)d_in[8];
    const float* w_ih_f = (const float*)d_in[9];  const float* w_hh_f = (const float*)d_in[10];
    const float* b_ih_f = (const float*)d_in[11]; const float* b_hh_f = (const float*)d_in[12];
    const float* w_ih_b = (const float*)d_in[13]; const float* w_hh_b = (const float*)d_in[14];
    const float* b_ih_b = (const float*)d_in[15]; const float* b_hh_b = (const float*)d_in[16];
    const float* fc_w = (const float*)d_in[17];  const float* fc_b = (const float*)d_in[18];
    float* out = (float*)d_out;

    const size_t PRE_BYTES = (size_t)BB * TT * HD * sizeof(ushort_t);  // 39,321,600
    char* p = (char*)d_ws;
    ushort_t* preF    = (ushort_t*)p;
    ushort_t* preB    = (ushort_t*)(p + PRE_BYTES);
    char* q = p + 2 * PRE_BYTES;
    ushort_t* wd_bf   = (ushort_t*)q;               q += 16384 * sizeof(ushort_t);
    ushort_t* wihf_bf = (ushort_t*)q;               q += 16384 * sizeof(ushort_t);
    ushort_t* wihb_bf = (ushort_t*)q;               q += 16384 * sizeof(ushort_t);
    ushort_t* whhf_bf = (ushort_t*)q;               q += 16384 * sizeof(ushort_t);
    ushort_t* whhb_bf = (ushort_t*)q;               q += 16384 * sizeof(ushort_t);
    float* bsf = (float*)q;                         q += 256 * sizeof(float);
    float* bsb = (float*)q;                         q += 256 * sizeof(float);
    float* ds  = (float*)q;

    prep_kernel<<<64, 256, 0, stream>>>(w_d, w_ih_f, w_ih_b, w_hh_f, w_hh_b,
                                        b_ih_f, b_hh_f, b_ih_b, b_hh_b,
                                        wd_bf, wihf_bf, wihb_bf, whhf_bf, whhb_bf, bsf, bsb);
    static_head_kernel<<<BB, 256, 0, stream>>>(x_static, norder, w_s1, b_s1, w_s2, b_s2,
                                               fc_w, fc_b, ds);
    proj_kernel<<<(BB * TT) / 128, 256, 0, stream>>>(x_dyn, wd_bf, b_d, wihf_bf, wihb_bf,
                                                     bsf, bsb, preF, preB);
    rnn_kernel<<<64, 64, 0, stream>>>(preF, preB, whhf_bf, whhb_bf);
    dot_kernel<<<640, 256, 0, stream>>>(preF, preB, fc_w, norder, ds, out);
}

// Round 7
// 295.573 us; speedup vs baseline: 1.2288x; 1.0315x over previous
//
#include <hip/hip_runtime.h>
#include <hip/hip_bf16.h>

#define BB 512
#define TT 300
#define IN_S 128
#define IN_D 64
#define HS 256
#define HD 128
#define CD 512  // 2*HD + HS

typedef __attribute__((ext_vector_type(8))) short bf16x8;
typedef __attribute__((ext_vector_type(4))) float f32x4;
typedef __attribute__((ext_vector_type(4))) unsigned uint4_t;
typedef unsigned short ushort_t;

static __device__ __forceinline__ ushort_t f2bf(float x) {
    unsigned u = __builtin_bit_cast(unsigned, x);
    unsigned r = (u + 0x7FFFu + ((u >> 16) & 1u)) >> 16;  // RNE
    return (ushort_t)r;
}
static __device__ __forceinline__ float bflo(unsigned u) {
    return __builtin_bit_cast(float, u << 16);
}
static __device__ __forceinline__ float bfhi(unsigned u) {
    return __builtin_bit_cast(float, u & 0xffff0000u);
}
static __device__ __forceinline__ unsigned cvt_pk(float lo, float hi) {
    unsigned r;
    asm("v_cvt_pk_bf16_f32 %0, %1, %2" : "=v"(r) : "v"(lo), "v"(hi));
    return r;
}

// ---------------------------------------------------------------------------
// prep: f32 weights -> bf16 workspace copies; fused RNN bias sums.
// ---------------------------------------------------------------------------
__global__ __launch_bounds__(256) void prep_kernel(
    const float* __restrict__ wd, const float* __restrict__ wihf, const float* __restrict__ wihb,
    const float* __restrict__ whhf, const float* __restrict__ whhb,
    const float* __restrict__ bif, const float* __restrict__ bhf,
    const float* __restrict__ bib, const float* __restrict__ bhb,
    ushort_t* __restrict__ wd_bf, ushort_t* __restrict__ wihf_bf, ushort_t* __restrict__ wihb_bf,
    ushort_t* __restrict__ whhf_bf, ushort_t* __restrict__ whhb_bf,
    float* __restrict__ bsf, float* __restrict__ bsb)
{
    const int i = blockIdx.x * 256 + threadIdx.x;  // < 16384
    if (i < HD * IN_D) wd_bf[i] = f2bf(wd[i]);
    wihf_bf[i] = f2bf(wihf[i]);
    wihb_bf[i] = f2bf(wihb[i]);
    whhf_bf[i] = f2bf(whhf[i]);
    whhb_bf[i] = f2bf(whhb[i]);
    if (i < HD) { bsf[i] = bif[i] + bhf[i]; bsb[i] = bib[i] + bhb[i]; }
}

// ---------------------------------------------------------------------------
// Kernel A (validated r0): static MLP + static head dot.
// ---------------------------------------------------------------------------
__global__ __launch_bounds__(256) void static_head_kernel(
    const float* __restrict__ xs, const int* __restrict__ norder,
    const float* __restrict__ w1, const float* __restrict__ b1,
    const float* __restrict__ w2, const float* __restrict__ b2,
    const float* __restrict__ fcw, const float* __restrict__ fcb,
    float* __restrict__ ds)
{
    __shared__ float xb[IN_S];
    __shared__ float s1[HS];
    __shared__ float red[4];
    const int b = blockIdx.x, tid = threadIdx.x;
    if (tid < IN_S) xb[tid] = xs[(size_t)b * IN_S + tid];
    __syncthreads();

    float a0 = 0.f, a1 = 0.f, a2 = 0.f, a3 = 0.f;
    {
        const float4* wsrc = (const float4*)(w1 + (size_t)tid * IN_S);
        const float4* x4 = (const float4*)xb;
#pragma unroll
        for (int i = 0; i < IN_S / 4; ++i) {
            float4 w = wsrc[i], x = x4[i];
            a0 = fmaf(w.x, x.x, a0); a1 = fmaf(w.y, x.y, a1);
            a2 = fmaf(w.z, x.z, a2); a3 = fmaf(w.w, x.w, a3);
        }
    }
    s1[tid] = fmaxf(b1[tid] + ((a0 + a1) + (a2 + a3)), 0.f);
    __syncthreads();

    a0 = a1 = a2 = a3 = 0.f;
    {
        const float4* wsrc = (const float4*)(w2 + (size_t)tid * HS);
        const float4* x4 = (const float4*)s1;
#pragma unroll
        for (int i = 0; i < HS / 4; ++i) {
            float4 w = wsrc[i], x = x4[i];
            a0 = fmaf(w.x, x.x, a0); a1 = fmaf(w.y, x.y, a1);
            a2 = fmaf(w.z, x.z, a2); a3 = fmaf(w.w, x.w, a3);
        }
    }
    float s2 = fmaxf(b2[tid] + ((a0 + a1) + (a2 + a3)), 0.f);

    const int n = norder[b];
    float p = s2 * fcw[(size_t)n * CD + tid];
#pragma unroll
    for (int o = 32; o >= 1; o >>= 1) p += __shfl_down(p, o);
    if ((tid & 63) == 0) red[tid >> 6] = p;
    __syncthreads();
    if (tid == 0) ds[b] = red[0] + red[1] + red[2] + red[3] + fcb[n];
}

// ---------------------------------------------------------------------------
// proj (validated r2, unchanged): MFMA bf16 projection + RNN input precompute.
// ---------------------------------------------------------------------------
__global__ __launch_bounds__(256) void proj_kernel(
    const float* __restrict__ xd, const ushort_t* __restrict__ wd_bf,
    const float* __restrict__ bd,
    const ushort_t* __restrict__ wihf_bf, const ushort_t* __restrict__ wihb_bf,
    const float* __restrict__ bsf, const float* __restrict__ bsb,
    ushort_t* __restrict__ preF, ushort_t* __restrict__ preB)
{
    __shared__ char lds[49152];
    char* dbase = lds;
    char* xbase = lds + 32768;
    const int tid = threadIdx.x;
    const int m0 = blockIdx.x * 128;

    {
        const int row = tid >> 1, half = tid & 1;
        const int swz = (row & 7) << 4;
        const float4* src = (const float4*)(xd + (size_t)(m0 + row) * IN_D + half * 32);
#pragma unroll
        for (int i = 0; i < 4; ++i) {
            float4 a = src[2 * i], b = src[2 * i + 1];
            bf16x8 v;
            v[0] = (short)f2bf(a.x); v[1] = (short)f2bf(a.y);
            v[2] = (short)f2bf(a.z); v[3] = (short)f2bf(a.w);
            v[4] = (short)f2bf(b.x); v[5] = (short)f2bf(b.y);
            v[6] = (short)f2bf(b.z); v[7] = (short)f2bf(b.w);
            *(bf16x8*)(xbase + ((row * 128 + half * 64 + i * 16) ^ swz)) = v;
        }
    }
    __syncthreads();

    const int w = tid >> 6, l = tid & 63;
    const int lr = l & 15, lg = l >> 4;

    f32x4 acc[2][8];
#pragma unroll
    for (int mt = 0; mt < 2; ++mt)
#pragma unroll
        for (int nt = 0; nt < 8; ++nt) acc[mt][nt] = (f32x4){0.f, 0.f, 0.f, 0.f};

    for (int kk = 0; kk < 2; ++kk) {
        bf16x8 a[2], b[8];
#pragma unroll
        for (int mt = 0; mt < 2; ++mt) {
            const int row = (w * 2 + mt) * 16 + lr;
            a[mt] = *(const bf16x8*)(xbase + ((row * 128 + kk * 64 + lg * 16) ^ ((row & 7) << 4)));
        }
#pragma unroll
        for (int nt = 0; nt < 8; ++nt)
            b[nt] = *(const bf16x8*)(wd_bf + (nt * 16 + lr) * IN_D + kk * 32 + lg * 8);
#pragma unroll
        for (int mt = 0; mt < 2; ++mt)
#pragma unroll
            for (int nt = 0; nt < 8; ++nt)
                acc[mt][nt] = __builtin_amdgcn_mfma_f32_16x16x32_bf16(a[mt], b[nt], acc[mt][nt], 0, 0, 0);
    }
#pragma unroll
    for (int nt = 0; nt < 8; ++nt) {
        const float bj = bd[nt * 16 + lr];
        const int col2 = (nt * 16 + lr) * 2;
#pragma unroll
        for (int mt = 0; mt < 2; ++mt)
#pragma unroll
            for (int r = 0; r < 4; ++r) {
                const int row = (w * 2 + mt) * 16 + lg * 4 + r;
                const float v = fmaxf(acc[mt][nt][r] + bj, 0.f);
                *(ushort_t*)(dbase + ((row * 256 + col2) ^ ((row & 7) << 4))) = f2bf(v);
            }
    }
    __syncthreads();

#pragma unroll
    for (int mat = 0; mat < 2; ++mat) {
        const ushort_t* wm = mat ? wihb_bf : wihf_bf;
        const float* bs = mat ? bsb : bsf;
        ushort_t* outp = mat ? preB : preF;

        f32x4 acc2[2][8];
#pragma unroll
        for (int mt = 0; mt < 2; ++mt)
#pragma unroll
            for (int nt = 0; nt < 8; ++nt) acc2[mt][nt] = (f32x4){0.f, 0.f, 0.f, 0.f};

        for (int kk = 0; kk < 4; ++kk) {
            bf16x8 a[2], b[8];
#pragma unroll
            for (int mt = 0; mt < 2; ++mt) {
                const int row = (w * 2 + mt) * 16 + lr;
                a[mt] = *(const bf16x8*)(dbase + ((row * 256 + kk * 64 + lg * 16) ^ ((row & 7) << 4)));
            }
#pragma unroll
            for (int nt = 0; nt < 8; ++nt)
                b[nt] = *(const bf16x8*)(wm + (nt * 16 + lr) * HD + kk * 32 + lg * 8);
#pragma unroll
            for (int mt = 0; mt < 2; ++mt)
#pragma unroll
                for (int nt = 0; nt < 8; ++nt)
                    acc2[mt][nt] = __builtin_amdgcn_mfma_f32_16x16x32_bf16(a[mt], b[nt], acc2[mt][nt], 0, 0, 0);
        }
        float bsv[8];
#pragma unroll
        for (int nt = 0; nt < 8; ++nt) bsv[nt] = bs[nt * 16 + lr];
#pragma unroll
        for (int mt = 0; mt < 2; ++mt)
#pragma unroll
            for (int r = 0; r < 4; ++r) {
                const unsigned m = (unsigned)(m0 + (w * 2 + mt) * 16 + lg * 4 + r);
                const unsigned s = m / TT, t = m % TT;
                ushort_t* rowp = outp + ((size_t)t * BB + s) * HD;
#pragma unroll
                for (int nt = 0; nt < 8; ++nt)
                    rowp[nt * 16 + lr] = f2bf(acc2[mt][nt][r] + bsv[nt]);
            }
    }
}

// ---------------------------------------------------------------------------
// rnn v7: v6's in-register recurrence, but h goes to a SEPARATE buffer
// (hF/hB) instead of in-place over pre. pre is const __restrict__, h is a
// distinct __restrict__ pointer -> no may-alias store->load serialization,
// the depth-2 prefetch can finally stay in flight (counted vmcnt, not 0).
// ---------------------------------------------------------------------------
__global__ __launch_bounds__(64, 1) void rnn_kernel(
    const ushort_t* __restrict__ preF, const ushort_t* __restrict__ preB,
    ushort_t* __restrict__ hF, ushort_t* __restrict__ hB,
    const ushort_t* __restrict__ whhF, const ushort_t* __restrict__ whhB)
{
    const int bid = blockIdx.x;
    const int dir = bid & 1;
    const int s0 = (bid >> 1) * 16;
    const ushort_t* __restrict__ pre = dir ? preB : preF;
    ushort_t* __restrict__ hout = dir ? hB : hF;
    const ushort_t* __restrict__ whh = dir ? whhB : whhF;

    const int l = threadIdx.x & 63;
    const int lr = l & 15, lg = l >> 4;

    // A fragments with permuted rows: tile jt, in-tile row m=lr -> whh row pi(jt,lr)
    bf16x8 Afrag[8][4];
#pragma unroll
    for (int jt = 0; jt < 8; ++jt) {
        const int row = (jt & 3) * 32 + (lr >> 2) * 8 + (jt >> 2) * 4 + (lr & 3);
#pragma unroll
        for (int kk = 0; kk < 4; ++kk)
            Afrag[jt][kk] = *(const bf16x8*)(whh + (size_t)row * HD + kk * 32 + lg * 8);
    }

    const int dt = dir ? -1 : 1;
    const int t0 = dir ? (TT - 1) : 0;
    const int base_off = (s0 + lr) * HD + lg * 8;  // + kk*32 covers j-quad pairs

    // packed h state (= next B fragments); h_{-1} = 0
    unsigned BQ[4][4];
#pragma unroll
    for (int kk = 0; kk < 4; ++kk)
#pragma unroll
        for (int q = 0; q < 4; ++q) BQ[kk][q] = 0u;

    // depth-2 register prefetch of pre (C operand): 4 x dwordx4 per buffer
    uint4_t pA[4], pB[4];
    {
        const ushort_t* p0 = pre + (size_t)t0 * (BB * HD) + base_off;
        const ushort_t* p1 = pre + (size_t)(t0 + dt) * (BB * HD) + base_off;
#pragma unroll
        for (int kk = 0; kk < 4; ++kk) {
            pA[kk] = *(const uint4_t*)(p0 + kk * 32);
            pB[kk] = *(const uint4_t*)(p1 + kk * 32);
        }
    }

    int t = t0;

#define RNN_STEP(P)                                                            \
    {                                                                          \
        f32x4 acc[8];                                                          \
        _Pragma("unroll")                                                      \
        for (int kk = 0; kk < 4; ++kk) {                                       \
            acc[kk][0] = bflo(P[kk].x);     acc[kk][1] = bfhi(P[kk].x);        \
            acc[kk][2] = bflo(P[kk].y);     acc[kk][3] = bfhi(P[kk].y);        \
            acc[kk + 4][0] = bflo(P[kk].z); acc[kk + 4][1] = bfhi(P[kk].z);    \
            acc[kk + 4][2] = bflo(P[kk].w); acc[kk + 4][3] = bfhi(P[kk].w);    \
        }                                                                      \
        _Pragma("unroll")                                                      \
        for (int kk = 0; kk < 4; ++kk) {                                       \
            const bf16x8 bq = __builtin_bit_cast(bf16x8,                       \
                (uint4_t){BQ[kk][0], BQ[kk][1], BQ[kk][2], BQ[kk][3]});        \
            _Pragma("unroll")                                                  \
            for (int jt = 0; jt < 8; ++jt)                                     \
                acc[jt] = __builtin_amdgcn_mfma_f32_16x16x32_bf16(             \
                    Afrag[jt][kk], bq, acc[jt], 0, 0, 0);                      \
        }                                                                      \
        _Pragma("unroll")                                                      \
        for (int jt = 0; jt < 8; ++jt) {                                       \
            const float v0 = fmaxf(acc[jt][0], 0.f);                           \
            const float v1 = fmaxf(acc[jt][1], 0.f);                           \
            const float v2 = fmaxf(acc[jt][2], 0.f);                           \
            const float v3 = fmaxf(acc[jt][3], 0.f);                           \
            const unsigned q01 = cvt_pk(v0, v1);                               \
            const unsigned q23 = cvt_pk(v2, v3);                               \
            if (jt < 4) { BQ[jt][0] = q01; BQ[jt][1] = q23; }                  \
            else        { BQ[jt - 4][2] = q01; BQ[jt - 4][3] = q23; }          \
        }                                                                      \
        {   /* store h (= BQ quads, j-contiguous) to the DISTINCT h buffer */  \
            ushort_t* hb = hout + (size_t)t * (BB * HD) + base_off;            \
            _Pragma("unroll")                                                  \
            for (int kk = 0; kk < 4; ++kk)                                     \
                *(uint4_t*)(hb + kk * 32) =                                    \
                    (uint4_t){BQ[kk][0], BQ[kk][1], BQ[kk][2], BQ[kk][3]};     \
        }                                                                      \
        const int tp = t + 2 * dt;                                             \
        const int tc = tp < 0 ? 0 : (tp >= TT ? TT - 1 : tp);                  \
        const ushort_t* pb = pre + (size_t)tc * (BB * HD) + base_off;          \
        _Pragma("unroll")                                                      \
        for (int kk = 0; kk < 4; ++kk) P[kk] = *(const uint4_t*)(pb + kk * 32);\
        t += dt;                                                               \
    }

    for (int it = 0; it < TT / 2; ++it) {
        RNN_STEP(pA);
        RNN_STEP(pB);
    }
#undef RNN_STEP
}

// ---------------------------------------------------------------------------
// dot (validated r2): out[s*T+t] = relu(ds[s] + hf[t,s,:].wgf + hb[t,s,:].wgb)
// ---------------------------------------------------------------------------
__global__ __launch_bounds__(256) void dot_kernel(
    const ushort_t* __restrict__ hF, const ushort_t* __restrict__ hB,
    const float* __restrict__ fcw, const int* __restrict__ norder,
    const float* __restrict__ ds, float* __restrict__ out)
{
    const int gw = blockIdx.x * 4 + (threadIdx.x >> 6);  // < 2560
    const int s = gw / 5, chunk = gw % 5;
    const int l = threadIdx.x & 63, lr = l & 15, lg = l >> 4;
    const int n = norder[s];
    const float4* wf4 = (const float4*)(fcw + (size_t)n * CD + HS);
    const float4* wb4 = (const float4*)(fcw + (size_t)n * CD + HS + HD);
    const float4 wf0 = wf4[lr * 2], wf1 = wf4[lr * 2 + 1];
    const float4 wb0 = wb4[lr * 2], wb1 = wb4[lr * 2 + 1];
    const float dsv = ds[s];

    for (int it = 0; it < 15; ++it) {
        const int t = chunk * 60 + it * 4 + lg;
        const size_t off = ((size_t)t * BB + s) * HD + lr * 8;
        const bf16x8 hf = *(const bf16x8*)(hF + off);
        const bf16x8 hb = *(const bf16x8*)(hB + off);
        float a = 0.f;
        a = fmaf(bflo((unsigned)(ushort_t)hf[0]), wf0.x, a);
        a = fmaf(bflo((unsigned)(ushort_t)hf[1]), wf0.y, a);
        a = fmaf(bflo((unsigned)(ushort_t)hf[2]), wf0.z, a);
        a = fmaf(bflo((unsigned)(ushort_t)hf[3]), wf0.w, a);
        a = fmaf(bflo((unsigned)(ushort_t)hf[4]), wf1.x, a);
        a = fmaf(bflo((unsigned)(ushort_t)hf[5]), wf1.y, a);
        a = fmaf(bflo((unsigned)(ushort_t)hf[6]), wf1.z, a);
        a = fmaf(bflo((unsigned)(ushort_t)hf[7]), wf1.w, a);
        a = fmaf(bflo((unsigned)(ushort_t)hb[0]), wb0.x, a);
        a = fmaf(bflo((unsigned)(ushort_t)hb[1]), wb0.y, a);
        a = fmaf(bflo((unsigned)(ushort_t)hb[2]), wb0.z, a);
        a = fmaf(bflo((unsigned)(ushort_t)hb[3]), wb0.w, a);
        a = fmaf(bflo((unsigned)(ushort_t)hb[4]), wb1.x, a);
        a = fmaf(bflo((unsigned)(ushort_t)hb[5]), wb1.y, a);
        a = fmaf(bflo((unsigned)(ushort_t)hb[6]), wb1.z, a);
        a = fmaf(bflo((unsigned)(ushort_t)hb[7]), wb1.w, a);
#pragma unroll
        for (int o = 1; o < 16; o <<= 1) a += __shfl_xor(a, o);
        if (lr == 0) out[s * TT + t] = fmaxf(a + dsv, 0.f);
    }
}

// ---------------------------------------------------------------------------
extern "C" void kernel_launch(void* const* d_in, const int* in_sizes, int n_in,
                              void* d_out, int out_size, void* d_ws, size_t ws_size,
                              hipStream_t stream)
{
    const float* x_static = (const float*)d_in[0];
    const float* x_dyn    = (const float*)d_in[1];
    const int*   norder   = (const int*)d_in[2];
    const float* w_s1 = (const float*)d_in[3];  const float* b_s1 = (const float*)d_in[4];
    const float* w_s2 = (const float*)d_in[5];  const float* b_s2 = (const float*)d_in[6];
    const float* w_d  = (const float*)d_in[7];  const float* b_d  = (const float*)d_in[8];
    const float* w_ih_f = (const float*)d_in[9];  const float* w_hh_f = (const float*)d_in[10];
    const float* b_ih_f = (const float*)d_in[11]; const float* b_hh_f = (const float*)d_in[12];
    const float* w_ih_b = (const float*)d_in[13]; const float* w_hh_b = (const float*)d_in[14];
    const float* b_ih_b = (const float*)d_in[15]; const float* b_hh_b = (const float*)d_in[16];
    const float* fc_w = (const float*)d_in[17];  const float* fc_b = (const float*)d_in[18];
    float* out = (float*)d_out;

    const size_t PRE_BYTES = (size_t)BB * TT * HD * sizeof(ushort_t);  // 39,321,600
    char* p = (char*)d_ws;
    ushort_t* preF    = (ushort_t*)p;
    ushort_t* preB    = (ushort_t*)(p + PRE_BYTES);
    ushort_t* hF      = (ushort_t*)(p + 2 * PRE_BYTES);
    ushort_t* hB      = (ushort_t*)(p + 3 * PRE_BYTES);
    char* q = p + 4 * PRE_BYTES;
    ushort_t* wd_bf   = (ushort_t*)q;               q += 16384 * sizeof(ushort_t);
    ushort_t* wihf_bf = (ushort_t*)q;               q += 16384 * sizeof(ushort_t);
    ushort_t* wihb_bf = (ushort_t*)q;               q += 16384 * sizeof(ushort_t);
    ushort_t* whhf_bf = (ushort_t*)q;               q += 16384 * sizeof(ushort_t);
    ushort_t* whhb_bf = (ushort_t*)q;               q += 16384 * sizeof(ushort_t);
    float* bsf = (float*)q;                         q += 256 * sizeof(float);
    float* bsb = (float*)q;                         q += 256 * sizeof(float);
    float* ds  = (float*)q;

    prep_kernel<<<64, 256, 0, stream>>>(w_d, w_ih_f, w_ih_b, w_hh_f, w_hh_b,
                                        b_ih_f, b_hh_f, b_ih_b, b_hh_b,
                                        wd_bf, wihf_bf, wihb_bf, whhf_bf, whhb_bf, bsf, bsb);
    static_head_kernel<<<BB, 256, 0, stream>>>(x_static, norder, w_s1, b_s1, w_s2, b_s2,
                                               fc_w, fc_b, ds);
    proj_kernel<<<(BB * TT) / 128, 256, 0, stream>>>(x_dyn, wd_bf, b_d, wihf_bf, wihb_bf,
                                                     bsf, bsb, preF, preB);
    rnn_kernel<<<64, 64, 0, stream>>>(preF, preB, hF, hB, whhf_bf, whhb_bf);
    dot_kernel<<<640, 256, 0, stream>>>(hF, hB, fc_w, norder, ds, out);
}